// Round 9
// baseline (139.525 us; speedup 1.0000x reference)
//
#include <hip/hip_runtime.h>

#define NWT   62500          // 1,000,000 rows / 16 rows per wave-tile
#define GRID  512
#define WPB   4              // waves per block (256 threads)
#define TOTW  (GRID * WPB)   // 2048 waves = exactly resident at 8 waves/CU

typedef __attribute__((ext_vector_type(8))) short bf16x8;
typedef __attribute__((ext_vector_type(4))) float f32x4;

static __device__ __forceinline__ short f2b(float f) {
    __bf16 h = (__bf16)f;                 // hardware RNE
    return __builtin_bit_cast(short, h);
}
static __device__ __forceinline__ unsigned pack2(float lo, float hi) {
    return ((unsigned)(unsigned short)f2b(lo)) |
           (((unsigned)(unsigned short)f2b(hi)) << 16);
}
static __device__ __forceinline__ float bflo(unsigned u) {
    return __builtin_bit_cast(float, u << 16);
}
static __device__ __forceinline__ float bfhi(unsigned u) {
    return __builtin_bit_cast(float, u & 0xffff0000u);
}
static __device__ __forceinline__ float tanh_fast(float x) {
    // tanh(x) = 1 - 2/(e^{2x}+1);  e^{2x} = exp2(x * 2*log2(e))
    float e = __builtin_exp2f(x * 2.8853900817779268f);
    return 1.0f - 2.0f * __builtin_amdgcn_rcpf(e + 1.0f);
}

// Swapped-operand gate, weights in registers: acc = Baug(A) x Xaug(B) + W^T(A) x S(B)
static __device__ __forceinline__ void gate_mm_reg(const bf16x8 (&wR)[2][4],
                                                   const char* lBg, const int (&baOff)[4],
                                                   bf16x8 aX, bf16x8 a0, bf16x8 a1,
                                                   f32x4 (&acc)[4])
{
    #pragma unroll
    for (int nt = 0; nt < 4; ++nt) {
        bf16x8 bx = *(const bf16x8*)(lBg + baOff[nt]);
        f32x4 z4 = {0.f, 0.f, 0.f, 0.f};
        acc[nt] = __builtin_amdgcn_mfma_f32_16x16x32_bf16(bx, aX, z4, 0, 0, 0);
    }
    #pragma unroll
    for (int ks = 0; ks < 2; ++ks) {
        bf16x8 a = ks ? a1 : a0;
        #pragma unroll
        for (int nt = 0; nt < 4; ++nt)
            acc[nt] = __builtin_amdgcn_mfma_f32_16x16x32_bf16(wR[ks][nt], a, acc[nt], 0, 0, 0);
    }
}

__global__ __launch_bounds__(256, 2)
void dgm_lstm_kernel(const float* __restrict__ S, const float* __restrict__ X,
                     const float* __restrict__ U0, const float* __restrict__ U1,
                     const float* __restrict__ U2, const float* __restrict__ U3,
                     const float* __restrict__ W0, const float* __restrict__ W1,
                     const float* __restrict__ W2, const float* __restrict__ W3,
                     const float* __restrict__ b0, const float* __restrict__ b1,
                     const float* __restrict__ b2, const float* __restrict__ b3,
                     float* __restrict__ Out)
{
    // gate order: 0=z, 1=g, 2=r, 3=h
    __shared__ __align__(16) unsigned short lWT[4][64][64];   // 32 KB: W^T bf16 (H reads [3] each tile)
    __shared__ __align__(16) unsigned short lBa[4][65][8];    // 4.1 KB
    __shared__ __align__(16) float          lS[WPB][16][68];  // 17 KB: S f32, wave-private
    __shared__ __align__(16) unsigned short lR[WPB][2][16][64];// 16 KB: (S*R) bf16, wave-private dbuf

    const int tid = threadIdx.x;

    // ---- one-time staging ----
    {
        const float* Ws[4] = {W0, W1, W2, W3};
        #pragma unroll
        for (int g = 0; g < 4; ++g) {
            #pragma unroll
            for (int it = 0; it < 8; ++it) {
                int p  = it * 256 + tid;            // 0..2047
                int n  = p & 63;
                int k2 = (p >> 6) << 1;
                float w0 = Ws[g][k2 * 64 + n];
                float w1 = Ws[g][k2 * 64 + 64 + n];
                int byt = ((n << 7) + (k2 << 1)) ^ ((n & 7) << 4);
                *(unsigned*)((char*)(&lWT[0][0][0]) + (g << 13) + byt) = pack2(w0, w1);
            }
        }
        const float* Us[4] = {U0, U1, U2, U3};
        const float* bs[4] = {b0, b1, b2, b3};
        int g = tid >> 6, n = tid & 63;
        bf16x8 f = {};
        f[0] = f2b(Us[g][n]);       f[1] = f2b(Us[g][64 + n]);
        f[2] = f2b(Us[g][128 + n]); f[3] = f2b(bs[g][n]);
        *(bf16x8*)(&lBa[g][n][0]) = f;
        if (tid < 4) { bf16x8 z = {}; *(bf16x8*)(&lBa[tid][64][0]) = z; }
    }
    __syncthreads();   // the only barrier; waves run independently below

    const int l   = tid & 63;
    const int wv  = tid >> 6;
    const int l15 = l & 15;
    const int lg  = l >> 4;

    const char* lWb = (const char*)(&lWT[0][0][0]);
    const char* lBb = (const char*)(&lBa[0][0][0]);
    char*       lRw = (char*)(&lR[wv][0][0][0]);    // 4 KB (2 x 2 KB buffers)

    // ---- weight A-fragments for Z,G,R in registers (96 regs); H stays in LDS ----
    bf16x8 wReg[3][2][4];
    #pragma unroll
    for (int g = 0; g < 3; ++g)
        #pragma unroll
        for (int ks = 0; ks < 2; ++ks)
            #pragma unroll
            for (int nt = 0; nt < 4; ++nt) {
                int n = l15 + (nt << 4);
                int byt = ((n << 7) + (ks << 6) + (lg << 4)) ^ ((n & 7) << 4);
                wReg[g][ks][nt] = *(const bf16x8*)(lWb + (g << 13) + byt);
            }

    // tile-invariant offsets
    int baOff[4];
    #pragma unroll
    for (int nt = 0; nt < 4; ++nt)
        baOff[nt] = ((lg == 0) ? (l15 + (nt << 4)) : 64) << 4;
    int wOffH[2][4];                      // H weight fragments (LDS)
    #pragma unroll
    for (int ks = 0; ks < 2; ++ks)
        #pragma unroll
        for (int nt = 0; nt < 4; ++nt) {
            int n = l15 + (nt << 4);
            wOffH[ks][nt] = ((n << 7) + (ks << 6) + (lg << 4)) ^ ((n & 7) << 4);
        }
    int wrOff[4];                         // lR write: row l15, cols nt*16+lg*4 (b64)
    #pragma unroll
    for (int nt = 0; nt < 4; ++nt)
        wrOff[nt] = ((l15 << 7) + (nt << 5) + (lg << 3)) ^ ((l15 & 7) << 4);
    int rdOff[2];                         // lR read: row l15, cols ks*32+lg*8 (b128)
    #pragma unroll
    for (int ks = 0; ks < 2; ++ks)
        rdOff[ks] = ((l15 << 7) + (ks << 6) + (lg << 4)) ^ ((l15 & 7) << 4);

    const int gw = blockIdx.x * WPB + wv;
    const short one_bf = (short)0x3F80;

    // ---- prologue prefetch (depth 1) ----
    float4 p0, p1, p2, p3;
    float  px0 = 0.f, px1 = 0.f, px2 = 0.f;
    {
        const float* Sr = S + (size_t)((gw << 4) + l15) * 64 + (lg << 3);
        p0 = *(const float4*)(Sr);      p1 = *(const float4*)(Sr + 4);
        p2 = *(const float4*)(Sr + 32); p3 = *(const float4*)(Sr + 36);
        if (lg == 0) {
            const float* Xr = X + (size_t)((gw << 4) + l15) * 3;
            px0 = Xr[0]; px1 = Xr[1]; px2 = Xr[2];
        }
    }

    // ---- carried pipeline state (tile t-1 -> its H executes next iteration) ----
    f32x4  zsC[4];          // z*s, f32
    uint2  gqp[4];          // (1-g) packed bf16 pairs
    bf16x8 aXp = {};
    int    rowH = 0, parH = 0, par = 0;

    // R,Z,G for tile wt; sets carried state; flips par
    auto RZG = [&](int wt) {
        const int row0 = wt << 4;

        // 1. stage S tile to wave-private LDS (f32, row l15, stride 68)
        float* lSr = &lS[wv][l15][0];
        *(float4*)(lSr + (lg << 3))      = p0;
        *(float4*)(lSr + (lg << 3) + 4)  = p1;
        *(float4*)(lSr + (lg << 3) + 32) = p2;
        *(float4*)(lSr + (lg << 3) + 36) = p3;

        // 2. bf16 B-fragments from the same registers
        bf16x8 aS0, aS1, aX = {};
        aS0[0] = f2b(p0.x); aS0[1] = f2b(p0.y); aS0[2] = f2b(p0.z); aS0[3] = f2b(p0.w);
        aS0[4] = f2b(p1.x); aS0[5] = f2b(p1.y); aS0[6] = f2b(p1.z); aS0[7] = f2b(p1.w);
        aS1[0] = f2b(p2.x); aS1[1] = f2b(p2.y); aS1[2] = f2b(p2.z); aS1[3] = f2b(p2.w);
        aS1[4] = f2b(p3.x); aS1[5] = f2b(p3.y); aS1[6] = f2b(p3.z); aS1[7] = f2b(p3.w);
        aX[0] = f2b(px0); aX[1] = f2b(px1); aX[2] = f2b(px2);
        aX[3] = (lg == 0) ? one_bf : (short)0;

        // 3. prefetch next tile (p regs free now; arrives ~a full tile early)
        int tn = wt + TOTW;
        if (tn < NWT) {
            const float* Sr = S + (size_t)((tn << 4) + l15) * 64 + (lg << 3);
            p0 = *(const float4*)(Sr);      p1 = *(const float4*)(Sr + 4);
            p2 = *(const float4*)(Sr + 32); p3 = *(const float4*)(Sr + 36);
            if (lg == 0) {
                const float* Xr = X + (size_t)((tn << 4) + l15) * 3;
                px0 = Xr[0]; px1 = Xr[1]; px2 = Xr[2];
            }
        }

        // 4. lS RAW fence (4 writes only outstanding), then row-per-lane sv
        asm volatile("s_waitcnt lgkmcnt(0)" ::: "memory");
        f32x4 sv[4];
        #pragma unroll
        for (int nt = 0; nt < 4; ++nt)
            sv[nt] = *(const f32x4*)(&lS[wv][l15][(nt << 4) + (lg << 2)]);

        f32x4 acc[4];

        // gate R: sr = sv * tanh(acc) in f32; write bf16 pairs into lR[par]
        char* lRp = lRw + (par << 11);
        gate_mm_reg(wReg[2], lBb + 2 * 1040, baOff, aX, aS0, aS1, acc);
        #pragma unroll
        for (int nt = 0; nt < 4; ++nt) {
            float sr0 = sv[nt][0] * tanh_fast(acc[nt][0]);
            float sr1 = sv[nt][1] * tanh_fast(acc[nt][1]);
            float sr2 = sv[nt][2] * tanh_fast(acc[nt][2]);
            float sr3 = sv[nt][3] * tanh_fast(acc[nt][3]);
            uint2 w;
            w.x = pack2(sr0, sr1);
            w.y = pack2(sr2, sr3);
            *(uint2*)(lRp + wrOff[nt]) = w;
        }

        // gate Z: zs = tanh * sv (carried f32)
        gate_mm_reg(wReg[0], lBb, baOff, aX, aS0, aS1, acc);
        #pragma unroll
        for (int nt = 0; nt < 4; ++nt)
            #pragma unroll
            for (int j = 0; j < 4; ++j)
                zsC[nt][j] = tanh_fast(acc[nt][j]) * sv[nt][j];

        // gate G: carry (1-g) packed bf16
        gate_mm_reg(wReg[1], lBb + 1040, baOff, aX, aS0, aS1, acc);
        #pragma unroll
        for (int nt = 0; nt < 4; ++nt) {
            float g0 = 1.0f - tanh_fast(acc[nt][0]);
            float g1 = 1.0f - tanh_fast(acc[nt][1]);
            float g2 = 1.0f - tanh_fast(acc[nt][2]);
            float g3 = 1.0f - tanh_fast(acc[nt][3]);
            gqp[nt].x = pack2(g0, g1);
            gqp[nt].y = pack2(g2, g3);
        }

        aXp = aX; rowH = row0; parH = par; par ^= 1;
    };

    // deferred H + combine + store for the tile staged one iteration ago
    auto HCOMB = [&]() {
        const char* lRp = lRw + (parH << 11);
        bf16x8 aR0 = *(const bf16x8*)(lRp + rdOff[0]);
        bf16x8 aR1 = *(const bf16x8*)(lRp + rdOff[1]);
        f32x4 acc[4];
        #pragma unroll
        for (int nt = 0; nt < 4; ++nt) {
            bf16x8 bx = *(const bf16x8*)(lBb + 3 * 1040 + baOff[nt]);
            f32x4 z4 = {0.f, 0.f, 0.f, 0.f};
            acc[nt] = __builtin_amdgcn_mfma_f32_16x16x32_bf16(bx, aXp, z4, 0, 0, 0);
        }
        #pragma unroll
        for (int ks = 0; ks < 2; ++ks) {
            bf16x8 a = ks ? aR1 : aR0;
            #pragma unroll
            for (int nt = 0; nt < 4; ++nt) {
                bf16x8 bw = *(const bf16x8*)(lWb + (3 << 13) + wOffH[ks][nt]);
                acc[nt] = __builtin_amdgcn_mfma_f32_16x16x32_bf16(bw, a, acc[nt], 0, 0, 0);
            }
        }
        float* Or = Out + (size_t)(rowH + l15) * 64 + (lg << 2);
        #pragma unroll
        for (int nt = 0; nt < 4; ++nt) {
            float4 o;
            o.x = fmaf(bflo(gqp[nt].x), tanh_fast(acc[nt][0]), zsC[nt][0]);
            o.y = fmaf(bfhi(gqp[nt].x), tanh_fast(acc[nt][1]), zsC[nt][1]);
            o.z = fmaf(bflo(gqp[nt].y), tanh_fast(acc[nt][2]), zsC[nt][2]);
            o.w = fmaf(bfhi(gqp[nt].y), tanh_fast(acc[nt][3]), zsC[nt][3]);
            *(float4*)(Or + (nt << 4)) = o;
        }
    };

    // ---- pipelined main loop (no block barriers, no sched fences) ----
    RZG(gw);
    for (int wt = gw + TOTW; wt < NWT; wt += TOTW) {
        HCOMB();        // H of tile t-1: lR writes are a full iteration old
        RZG(wt);        // R,Z,G of tile t
    }
    HCOMB();            // drain
}

extern "C" void kernel_launch(void* const* d_in, const int* in_sizes, int n_in,
                              void* d_out, int out_size, void* d_ws, size_t ws_size,
                              hipStream_t stream) {
    dim3 grid(GRID), block(256);
    dgm_lstm_kernel<<<grid, block, 0, stream>>>(
        (const float*)d_in[0],  (const float*)d_in[1],
        (const float*)d_in[2],  (const float*)d_in[3],
        (const float*)d_in[4],  (const float*)d_in[5],
        (const float*)d_in[6],  (const float*)d_in[7],
        (const float*)d_in[8],  (const float*)d_in[9],
        (const float*)d_in[10], (const float*)d_in[11],
        (const float*)d_in[12], (const float*)d_in[13],
        (float*)d_out);
}

// Round 10
// 118.917 us; speedup vs baseline: 1.1733x; 1.1733x over previous
//
#include <hip/hip_runtime.h>

#define NWT   62500          // 1,000,000 rows / 16 rows per wave-tile
#define GRID  512
#define WPB   4              // waves per block (256 threads)
#define TOTW  (GRID * WPB)   // 2048 waves

typedef __attribute__((ext_vector_type(8))) short bf16x8;
typedef __attribute__((ext_vector_type(4))) float f32x4;

static __device__ __forceinline__ short f2b(float f) {
    __bf16 h = (__bf16)f;                 // hardware RNE
    return __builtin_bit_cast(short, h);
}
static __device__ __forceinline__ unsigned pack2(float lo, float hi) {
    return ((unsigned)(unsigned short)f2b(lo)) |
           (((unsigned)(unsigned short)f2b(hi)) << 16);
}
static __device__ __forceinline__ float tanh_fast(float x) {
    float e = __expf(2.0f * x);           // v_mul + v_exp (proven fast path)
    return 1.0f - 2.0f * __builtin_amdgcn_rcpf(e + 1.0f);
}

// Swapped-operand gate, weights in registers: acc = Baug(A) x Xaug(B) + W^T(A) x S(B)
static __device__ __forceinline__ void gate_mm_reg(const bf16x8 (&wR)[2][4],
                                                   const char* lBg, const int (&baOff)[4],
                                                   bf16x8 aX, bf16x8 a0, bf16x8 a1,
                                                   f32x4 (&acc)[4])
{
    #pragma unroll
    for (int nt = 0; nt < 4; ++nt) {
        bf16x8 bx = *(const bf16x8*)(lBg + baOff[nt]);
        f32x4 z4 = {0.f, 0.f, 0.f, 0.f};
        acc[nt] = __builtin_amdgcn_mfma_f32_16x16x32_bf16(bx, aX, z4, 0, 0, 0);
    }
    #pragma unroll
    for (int ks = 0; ks < 2; ++ks) {
        bf16x8 a = ks ? a1 : a0;
        #pragma unroll
        for (int nt = 0; nt < 4; ++nt)
            acc[nt] = __builtin_amdgcn_mfma_f32_16x16x32_bf16(wR[ks][nt], a, acc[nt], 0, 0, 0);
    }
}

__global__ __launch_bounds__(256, 2)
void dgm_lstm_kernel(const float* __restrict__ S, const float* __restrict__ X,
                     const float* __restrict__ U0, const float* __restrict__ U1,
                     const float* __restrict__ U2, const float* __restrict__ U3,
                     const float* __restrict__ W0, const float* __restrict__ W1,
                     const float* __restrict__ W2, const float* __restrict__ W3,
                     const float* __restrict__ b0, const float* __restrict__ b1,
                     const float* __restrict__ b2, const float* __restrict__ b3,
                     float* __restrict__ Out)
{
    // gate order: 0=z, 1=g, 2=r, 3=h
    __shared__ __align__(16) unsigned short lWT[4][64][64];   // 32 KB: W^T bf16 (H reads [3] each tile)
    __shared__ __align__(16) unsigned short lBa[4][65][8];    // 4.1 KB
    __shared__ __align__(16) float          lS[WPB][16][68];  // 17 KB: S f32, wave-private
    __shared__ __align__(16) unsigned short lR[WPB][2][16][64];// 16 KB: (S*R) bf16, wave-private dbuf

    const int tid = threadIdx.x;

    // ---- one-time staging ----
    {
        const float* Ws[4] = {W0, W1, W2, W3};
        #pragma unroll
        for (int g = 0; g < 4; ++g) {
            #pragma unroll
            for (int it = 0; it < 8; ++it) {
                int p  = it * 256 + tid;            // 0..2047
                int n  = p & 63;
                int k2 = (p >> 6) << 1;
                float w0 = Ws[g][k2 * 64 + n];
                float w1 = Ws[g][k2 * 64 + 64 + n];
                int byt = ((n << 7) + (k2 << 1)) ^ ((n & 7) << 4);
                *(unsigned*)((char*)(&lWT[0][0][0]) + (g << 13) + byt) = pack2(w0, w1);
            }
        }
        const float* Us[4] = {U0, U1, U2, U3};
        const float* bs[4] = {b0, b1, b2, b3};
        int g = tid >> 6, n = tid & 63;
        bf16x8 f = {};
        f[0] = f2b(Us[g][n]);       f[1] = f2b(Us[g][64 + n]);
        f[2] = f2b(Us[g][128 + n]); f[3] = f2b(bs[g][n]);
        *(bf16x8*)(&lBa[g][n][0]) = f;
        if (tid < 4) { bf16x8 z = {}; *(bf16x8*)(&lBa[tid][64][0]) = z; }
    }
    __syncthreads();   // the only barrier; waves run independently below

    const int l   = tid & 63;
    const int wv  = tid >> 6;
    const int l15 = l & 15;
    const int lg  = l >> 4;

    const char* lWb = (const char*)(&lWT[0][0][0]);
    const char* lBb = (const char*)(&lBa[0][0][0]);
    char*       lRw = (char*)(&lR[wv][0][0][0]);    // 4 KB (2 x 2 KB buffers)

    // ---- weight A-fragments for Z,G,R in registers (96 regs); H stays in LDS ----
    bf16x8 wReg[3][2][4];
    #pragma unroll
    for (int g = 0; g < 3; ++g)
        #pragma unroll
        for (int ks = 0; ks < 2; ++ks)
            #pragma unroll
            for (int nt = 0; nt < 4; ++nt) {
                int n = l15 + (nt << 4);
                int byt = ((n << 7) + (ks << 6) + (lg << 4)) ^ ((n & 7) << 4);
                wReg[g][ks][nt] = *(const bf16x8*)(lWb + (g << 13) + byt);
            }

    // tile-invariant offsets
    int baOff[4];
    #pragma unroll
    for (int nt = 0; nt < 4; ++nt)
        baOff[nt] = ((lg == 0) ? (l15 + (nt << 4)) : 64) << 4;
    int wOffH[2][4];                      // H weight fragments (LDS)
    #pragma unroll
    for (int ks = 0; ks < 2; ++ks)
        #pragma unroll
        for (int nt = 0; nt < 4; ++nt) {
            int n = l15 + (nt << 4);
            wOffH[ks][nt] = ((n << 7) + (ks << 6) + (lg << 4)) ^ ((n & 7) << 4);
        }
    int wrOff[4];                         // lR write: row l15, cols nt*16+lg*4 (b64)
    #pragma unroll
    for (int nt = 0; nt < 4; ++nt)
        wrOff[nt] = ((l15 << 7) + (nt << 5) + (lg << 3)) ^ ((l15 & 7) << 4);
    int rdOff[2];                         // lR read: row l15, cols ks*32+lg*8 (b128)
    #pragma unroll
    for (int ks = 0; ks < 2; ++ks)
        rdOff[ks] = ((l15 << 7) + (ks << 6) + (lg << 4)) ^ ((l15 & 7) << 4);

    const int gw = blockIdx.x * WPB + wv;
    const short one_bf = (short)0x3F80;

    // ---- prologue prefetch (depth 1) ----
    float4 p0, p1, p2, p3;
    float  px0 = 0.f, px1 = 0.f, px2 = 0.f;
    {
        const float* Sr = S + (size_t)((gw << 4) + l15) * 64 + (lg << 3);
        p0 = *(const float4*)(Sr);      p1 = *(const float4*)(Sr + 4);
        p2 = *(const float4*)(Sr + 32); p3 = *(const float4*)(Sr + 36);
        if (lg == 0) {
            const float* Xr = X + (size_t)((gw << 4) + l15) * 3;
            px0 = Xr[0]; px1 = Xr[1]; px2 = Xr[2];
        }
    }

    // ---- carried pipeline state (tile t-1 -> its H executes next iteration) ----
    f32x4  zsC[4];          // z*s, f32
    f32x4  gqC[4];          // 1-g, f32
    bf16x8 aXp = {};
    int    rowH = 0, parH = 0, par = 0;

    // R,Z,G for tile wt; sets carried state; flips par
    auto RZG = [&](int wt) {
        const int row0 = wt << 4;

        // 1. stage S tile to wave-private LDS (f32, row l15, stride 68)
        float* lSr = &lS[wv][l15][0];
        *(float4*)(lSr + (lg << 3))      = p0;
        *(float4*)(lSr + (lg << 3) + 4)  = p1;
        *(float4*)(lSr + (lg << 3) + 32) = p2;
        *(float4*)(lSr + (lg << 3) + 36) = p3;

        // 2. bf16 B-fragments from the same registers
        bf16x8 aS0, aS1, aX = {};
        aS0[0] = f2b(p0.x); aS0[1] = f2b(p0.y); aS0[2] = f2b(p0.z); aS0[3] = f2b(p0.w);
        aS0[4] = f2b(p1.x); aS0[5] = f2b(p1.y); aS0[6] = f2b(p1.z); aS0[7] = f2b(p1.w);
        aS1[0] = f2b(p2.x); aS1[1] = f2b(p2.y); aS1[2] = f2b(p2.z); aS1[3] = f2b(p2.w);
        aS1[4] = f2b(p3.x); aS1[5] = f2b(p3.y); aS1[6] = f2b(p3.z); aS1[7] = f2b(p3.w);
        aX[0] = f2b(px0); aX[1] = f2b(px1); aX[2] = f2b(px2);
        aX[3] = (lg == 0) ? one_bf : (short)0;

        // 3. prefetch next tile
        int tn = wt + TOTW;
        if (tn < NWT) {
            const float* Sr = S + (size_t)((tn << 4) + l15) * 64 + (lg << 3);
            p0 = *(const float4*)(Sr);      p1 = *(const float4*)(Sr + 4);
            p2 = *(const float4*)(Sr + 32); p3 = *(const float4*)(Sr + 36);
            if (lg == 0) {
                const float* Xr = X + (size_t)((tn << 4) + l15) * 3;
                px0 = Xr[0]; px1 = Xr[1]; px2 = Xr[2];
            }
        }

        // 4. lS RAW fence, then row-per-lane sv
        asm volatile("s_waitcnt lgkmcnt(0)" ::: "memory");
        f32x4 sv[4];
        #pragma unroll
        for (int nt = 0; nt < 4; ++nt)
            sv[nt] = *(const f32x4*)(&lS[wv][l15][(nt << 4) + (lg << 2)]);

        f32x4 acc[4];

        // gate R: sr = sv * tanh(acc) in f32; write bf16 pairs into lR[par]
        char* lRp = lRw + (par << 11);
        gate_mm_reg(wReg[2], lBb + 2 * 1040, baOff, aX, aS0, aS1, acc);
        #pragma unroll
        for (int nt = 0; nt < 4; ++nt) {
            float sr0 = sv[nt][0] * tanh_fast(acc[nt][0]);
            float sr1 = sv[nt][1] * tanh_fast(acc[nt][1]);
            float sr2 = sv[nt][2] * tanh_fast(acc[nt][2]);
            float sr3 = sv[nt][3] * tanh_fast(acc[nt][3]);
            uint2 w;
            w.x = pack2(sr0, sr1);
            w.y = pack2(sr2, sr3);
            *(uint2*)(lRp + wrOff[nt]) = w;
        }

        // gate Z: zs = tanh * sv (carried f32)
        gate_mm_reg(wReg[0], lBb, baOff, aX, aS0, aS1, acc);
        #pragma unroll
        for (int nt = 0; nt < 4; ++nt)
            #pragma unroll
            for (int j = 0; j < 4; ++j)
                zsC[nt][j] = tanh_fast(acc[nt][j]) * sv[nt][j];

        // gate G: carried (1-g) f32
        gate_mm_reg(wReg[1], lBb + 1040, baOff, aX, aS0, aS1, acc);
        #pragma unroll
        for (int nt = 0; nt < 4; ++nt)
            #pragma unroll
            for (int j = 0; j < 4; ++j)
                gqC[nt][j] = 1.0f - tanh_fast(acc[nt][j]);

        aXp = aX; rowH = row0; parH = par; par ^= 1;
    };

    // deferred H + combine + store for the tile staged one iteration ago
    auto HCOMB = [&]() {
        const char* lRp = lRw + (parH << 11);
        bf16x8 aR0 = *(const bf16x8*)(lRp + rdOff[0]);
        bf16x8 aR1 = *(const bf16x8*)(lRp + rdOff[1]);
        f32x4 acc[4];
        #pragma unroll
        for (int nt = 0; nt < 4; ++nt) {
            bf16x8 bx = *(const bf16x8*)(lBb + 3 * 1040 + baOff[nt]);
            f32x4 z4 = {0.f, 0.f, 0.f, 0.f};
            acc[nt] = __builtin_amdgcn_mfma_f32_16x16x32_bf16(bx, aXp, z4, 0, 0, 0);
        }
        #pragma unroll
        for (int ks = 0; ks < 2; ++ks) {
            bf16x8 a = ks ? aR1 : aR0;
            #pragma unroll
            for (int nt = 0; nt < 4; ++nt) {
                bf16x8 bw = *(const bf16x8*)(lWb + (3 << 13) + wOffH[ks][nt]);
                acc[nt] = __builtin_amdgcn_mfma_f32_16x16x32_bf16(bw, a, acc[nt], 0, 0, 0);
            }
        }
        float* Or = Out + (size_t)(rowH + l15) * 64 + (lg << 2);
        #pragma unroll
        for (int nt = 0; nt < 4; ++nt) {
            float4 o;
            o.x = fmaf(gqC[nt][0], tanh_fast(acc[nt][0]), zsC[nt][0]);
            o.y = fmaf(gqC[nt][1], tanh_fast(acc[nt][1]), zsC[nt][1]);
            o.z = fmaf(gqC[nt][2], tanh_fast(acc[nt][2]), zsC[nt][2]);
            o.w = fmaf(gqC[nt][3], tanh_fast(acc[nt][3]), zsC[nt][3]);
            *(float4*)(Or + (nt << 4)) = o;
        }
    };

    // ---- pipelined main loop (no block barriers, no sched fences) ----
    RZG(gw);
    for (int wt = gw + TOTW; wt < NWT; wt += TOTW) {
        HCOMB();        // H of tile t-1: lR writes are a full iteration old
        RZG(wt);        // R,Z,G of tile t
    }
    HCOMB();            // drain
}

extern "C" void kernel_launch(void* const* d_in, const int* in_sizes, int n_in,
                              void* d_out, int out_size, void* d_ws, size_t ws_size,
                              hipStream_t stream) {
    dim3 grid(GRID), block(256);
    dgm_lstm_kernel<<<grid, block, 0, stream>>>(
        (const float*)d_in[0],  (const float*)d_in[1],
        (const float*)d_in[2],  (const float*)d_in[3],
        (const float*)d_in[4],  (const float*)d_in[5],
        (const float*)d_in[6],  (const float*)d_in[7],
        (const float*)d_in[8],  (const float*)d_in[9],
        (const float*)d_in[10], (const float*)d_in[11],
        (const float*)d_in[12], (const float*)d_in[13],
        (float*)d_out);
}